// Round 7
// baseline (937.765 us; speedup 1.0000x reference)
//
#include <hip/hip_runtime.h>
#include <hip/hip_bf16.h>
#include <math.h>

// FleetModel forward. Round 7: quad-sliced fused row engine.
// R5 lesson: VGPR cap -> HBM spill. R6 lesson: partial unroll -> runtime
// indices -> scratch demotion (VGPR=68, VALUBusy 4.6%). This round: FULL
// unroll (all compile-time indices) + uncapped allocator.
#define NB 128
#define NPOS 652
#define DD 32
#define NH 4
#define NVEH 64
#define ZSTRIDE 162          // 2 + 16*10
#define MROWS (NB*NPOS)      // 83456 = 1304 * 64
#define QSCALE 0.51011784f   // (1/sqrt(8)) * log2(e)

typedef _Float16 half4 __attribute__((ext_vector_type(4)));
typedef _Float16 half8 __attribute__((ext_vector_type(8)));
typedef float float4v __attribute__((ext_vector_type(4)));

__device__ __forceinline__ float wave_sum64(float v) {
  #pragma unroll
  for (int off = 32; off > 0; off >>= 1) v += __shfl_down(v, off);
  return v;
}

// ---------------------------------------------------------------- canvas ----
__global__ __launch_bounds__(256) void canvas_kernel(
    const float* __restrict__ states, const float* __restrict__ road_ctx,
    const float* __restrict__ pos_emb,
    const float* __restrict__ Wp, const float* __restrict__ bp,
    const float* __restrict__ Wv, const float* __restrict__ bv,
    const float* __restrict__ Wh, const float* __restrict__ bh,
    const float* __restrict__ Wc, const float* __restrict__ bc,
    const float* __restrict__ Wflow, const float* __restrict__ bflow,
    const float* __restrict__ Wsig, const float* __restrict__ bsig,
    float* __restrict__ x)
{
  int b = blockIdx.x;
  int tid = threadIdx.x;
  __shared__ float mvs[2];
  if (tid < 64) {
    float vx = states[(b*NVEH + tid)*4 + 2];
    float vy = states[(b*NVEH + tid)*4 + 3];
    vx = wave_sum64(vx); vy = wave_sum64(vy);
    if (tid == 0) { mvs[0] = vx * (1.f/64.f); mvs[1] = vy * (1.f/64.f); }
  }
  __syncthreads();
  float mv0 = mvs[0], mv1 = mvs[1];
  for (int i = tid; i < NPOS*DD; i += 256) {
    int p = i >> 5, d = i & 31;
    float val = pos_emb[i];
    if (p < 4) {
      val += mv0*Wflow[p*32 + d] + mv1*Wflow[128 + p*32 + d] + bflow[p*32 + d];
    } else {
      int q = p - 4, z = q / ZSTRIDE, r = q % ZSTRIDE;
      if (r == 0) {
        val += Wsig[d] + bsig[d];
      } else if (r >= 2) {
        int vr = r - 2, v = vr / 10, s = vr % 10;
        int n = z*16 + v;
        const float* st = states + (b*NVEH + n)*4;
        if (s == 0) {
          val += st[0]*Wp[d] + st[1]*Wp[32+d] + bp[d];
        } else if (s == 1) {
          val += st[2]*Wv[d] + st[3]*Wv[32+d] + bv[d];
        } else if (s == 2) {
          float sp = fmaxf(sqrtf(st[2]*st[2] + st[3]*st[3]), 0.1f);
          val += (st[2]/sp)*Wh[d] + (st[3]/sp)*Wh[32+d] + bh[d];
        } else if (s == 3) {
          const float* rc = road_ctx + (b*NVEH + n)*4;
          val += rc[0]*Wc[d] + rc[1]*Wc[32+d] + rc[2]*Wc[64+d] + rc[3]*Wc[96+d] + bc[d];
        }
      }
    }
    x[(size_t)b*NPOS*DD + i] = val;
  }
}

// ------------------------------------------------------------ slice engine ----
// Quad-sliced: row = blockIdx.x*64 + tid/4, slice s = tid&3.
// All cross-slice traffic via in-quad shuffles; no LDS, no barriers.
// EVERY loop fully unrolled -> all arrays live in registers (rule #20).
template<bool DO_PROJ, bool DO_QKV>
__global__ __launch_bounds__(256) void slice_kernel(
    const float* __restrict__ ob, const float* __restrict__ x_in,
    float* __restrict__ x_out,
    const float* __restrict__ Wo, const float* __restrict__ bo,
    const float* __restrict__ g1v, const float* __restrict__ b1v,
    const float* __restrict__ W1, const float* __restrict__ b1f,
    const float* __restrict__ W2, const float* __restrict__ b2f,
    const float* __restrict__ g2v, const float* __restrict__ b2v,
    const float* __restrict__ Wqkv, const float* __restrict__ bqkv,
    _Float16* __restrict__ qkh, _Float16* __restrict__ kbh,
    _Float16* __restrict__ vth)
{
  const int tid = threadIdx.x;
  const int s = tid & 3;
  const int lane = tid & 63;
  const int qbase = lane & 60;                 // quad base lane (in-wave)
  const unsigned row = blockIdx.x*64u + (unsigned)(tid >> 2);

  float xr[32];   // full new-x row (for QKV)
  float x8[8];    // lane's 8 cols of new x

  if (DO_PROJ) {
    // ---- proj slice: t8 = (o @ Wo + bo)[8s..8s+8] + x_in resid
    float t8[8];
    {
      float4 b0 = *(const float4*)(bo + 8*s);
      float4 b1 = *(const float4*)(bo + 8*s + 4);
      t8[0]=b0.x; t8[1]=b0.y; t8[2]=b0.z; t8[3]=b0.w;
      t8[4]=b1.x; t8[5]=b1.y; t8[6]=b1.z; t8[7]=b1.w;
    }
    {
      float orow[32];
      const float4* op = (const float4*)(ob + (size_t)row*32);
      #pragma unroll
      for (int i = 0; i < 8; ++i) {
        float4 t = op[i];
        orow[4*i]=t.x; orow[4*i+1]=t.y; orow[4*i+2]=t.z; orow[4*i+3]=t.w;
      }
      #pragma unroll
      for (int k = 0; k < 32; ++k) {
        float ov = orow[k];
        float4 w0 = *(const float4*)(Wo + k*32 + 8*s);
        float4 w1 = *(const float4*)(Wo + k*32 + 8*s + 4);
        t8[0]+=ov*w0.x; t8[1]+=ov*w0.y; t8[2]+=ov*w0.z; t8[3]+=ov*w0.w;
        t8[4]+=ov*w1.x; t8[5]+=ov*w1.y; t8[6]+=ov*w1.z; t8[7]+=ov*w1.w;
      }
    }
    {
      const float4* xp = (const float4*)(x_in + (size_t)row*32 + 8*s);
      float4 r0 = xp[0], r1 = xp[1];
      t8[0]+=r0.x; t8[1]+=r0.y; t8[2]+=r0.z; t8[3]+=r0.w;
      t8[4]+=r1.x; t8[5]+=r1.y; t8[6]+=r1.z; t8[7]+=r1.w;
    }
    // ---- LN1 (quad reduce)
    float s1 = 0.f, s2 = 0.f;
    #pragma unroll
    for (int j = 0; j < 8; ++j) { s1 += t8[j]; s2 += t8[j]*t8[j]; }
    s1 += __shfl_xor(s1, 1); s1 += __shfl_xor(s1, 2);
    s2 += __shfl_xor(s2, 1); s2 += __shfl_xor(s2, 2);
    float m = s1*(1.f/32.f);
    float rinv = rsqrtf(s2*(1.f/32.f) - m*m + 1e-5f);
    float y8[8];
    {
      float4 ga = *(const float4*)(g1v + 8*s);
      float4 gb = *(const float4*)(g1v + 8*s + 4);
      float4 ba = *(const float4*)(b1v + 8*s);
      float4 bb = *(const float4*)(b1v + 8*s + 4);
      y8[0]=(t8[0]-m)*rinv*ga.x+ba.x; y8[1]=(t8[1]-m)*rinv*ga.y+ba.y;
      y8[2]=(t8[2]-m)*rinv*ga.z+ba.z; y8[3]=(t8[3]-m)*rinv*ga.w+ba.w;
      y8[4]=(t8[4]-m)*rinv*gb.x+bb.x; y8[5]=(t8[5]-m)*rinv*gb.y+bb.y;
      y8[6]=(t8[6]-m)*rinv*gb.z+bb.z; y8[7]=(t8[7]-m)*rinv*gb.w+bb.w;
    }
    // ---- assemble full y row (in-quad bpermutes)
    float yr[32];
    #pragma unroll
    for (int c = 0; c < 4; ++c)
      #pragma unroll
      for (int j = 0; j < 8; ++j)
        yr[8*c + j] = __shfl(y8[j], qbase + c);
    // ---- FFN W1 slice (32 hidden cols) + relu, then W2 partials
    float h[32];
    #pragma unroll
    for (int i = 0; i < 8; ++i) {
      float4 bb = *(const float4*)(b1f + 32*s + 4*i);
      h[4*i]=bb.x; h[4*i+1]=bb.y; h[4*i+2]=bb.z; h[4*i+3]=bb.w;
    }
    #pragma unroll
    for (int k = 0; k < 32; ++k) {
      float yv = yr[k];
      const float* wr = W1 + k*128 + 32*s;
      #pragma unroll
      for (int i = 0; i < 8; ++i) {
        float4 wv = *(const float4*)(wr + 4*i);
        h[4*i]+=yv*wv.x; h[4*i+1]+=yv*wv.y; h[4*i+2]+=yv*wv.z; h[4*i+3]+=yv*wv.w;
      }
    }
    #pragma unroll
    for (int c = 0; c < 32; ++c) h[c] = fmaxf(h[c], 0.f);
    float z[32];
    #pragma unroll
    for (int j = 0; j < 32; ++j) z[j] = 0.f;
    #pragma unroll
    for (int c = 0; c < 32; ++c) {
      float hv = h[c];
      const float* wr = W2 + (32*s + c)*32;
      #pragma unroll
      for (int i = 0; i < 8; ++i) {
        float4 wv = *(const float4*)(wr + 4*i);
        z[4*i]+=hv*wv.x; z[4*i+1]+=hv*wv.y; z[4*i+2]+=hv*wv.z; z[4*i+3]+=hv*wv.w;
      }
    }
    // ---- butterfly reduce: lane ends with full sums for cols 8s..8s+7
    float zz[16];
    #pragma unroll
    for (int j = 0; j < 16; ++j) {            // step A: xor 2 (col halves)
      float keep = (s & 2) ? z[j+16] : z[j];
      float send = (s & 2) ? z[j]    : z[j+16];
      zz[j] = keep + __shfl_xor(send, 2);
    }
    float y2[8];
    #pragma unroll
    for (int j = 0; j < 8; ++j) {             // step B: xor 1 (col quarters)
      float keep = (s & 1) ? zz[j+8] : zz[j];
      float send = (s & 1) ? zz[j]   : zz[j+8];
      y2[j] = keep + __shfl_xor(send, 1);
    }
    {
      float4 ba = *(const float4*)(b2f + 8*s);
      float4 bb = *(const float4*)(b2f + 8*s + 4);
      y2[0]+=ba.x+y8[0]; y2[1]+=ba.y+y8[1]; y2[2]+=ba.z+y8[2]; y2[3]+=ba.w+y8[3];
      y2[4]+=bb.x+y8[4]; y2[5]+=bb.y+y8[5]; y2[6]+=bb.z+y8[6]; y2[7]+=bb.w+y8[7];
    }
    // ---- LN2 (quad reduce)
    float u1 = 0.f, u2 = 0.f;
    #pragma unroll
    for (int j = 0; j < 8; ++j) { u1 += y2[j]; u2 += y2[j]*y2[j]; }
    u1 += __shfl_xor(u1, 1); u1 += __shfl_xor(u1, 2);
    u2 += __shfl_xor(u2, 1); u2 += __shfl_xor(u2, 2);
    float m2 = u1*(1.f/32.f);
    float rinv2 = rsqrtf(u2*(1.f/32.f) - m2*m2 + 1e-5f);
    {
      float4 ga = *(const float4*)(g2v + 8*s);
      float4 gb = *(const float4*)(g2v + 8*s + 4);
      float4 ba = *(const float4*)(b2v + 8*s);
      float4 bb = *(const float4*)(b2v + 8*s + 4);
      x8[0]=(y2[0]-m2)*rinv2*ga.x+ba.x; x8[1]=(y2[1]-m2)*rinv2*ga.y+ba.y;
      x8[2]=(y2[2]-m2)*rinv2*ga.z+ba.z; x8[3]=(y2[3]-m2)*rinv2*ga.w+ba.w;
      x8[4]=(y2[4]-m2)*rinv2*gb.x+bb.x; x8[5]=(y2[5]-m2)*rinv2*gb.y+bb.y;
      x8[6]=(y2[6]-m2)*rinv2*gb.z+bb.z; x8[7]=(y2[7]-m2)*rinv2*gb.w+bb.w;
    }
    {
      float4* xo = (float4*)(x_out + (size_t)row*32 + 8*s);
      xo[0] = make_float4(x8[0],x8[1],x8[2],x8[3]);
      xo[1] = make_float4(x8[4],x8[5],x8[6],x8[7]);
    }
    if (DO_QKV) {
      #pragma unroll
      for (int c = 0; c < 4; ++c)
        #pragma unroll
        for (int j = 0; j < 8; ++j)
          xr[8*c + j] = __shfl(x8[j], qbase + c);
    }
  } else if (DO_QKV) {
    const float4* xp = (const float4*)(x_in + (size_t)row*32);
    #pragma unroll
    for (int i = 0; i < 8; ++i) {
      float4 t = xp[i];
      xr[4*i]=t.x; xr[4*i+1]=t.y; xr[4*i+2]=t.z; xr[4*i+3]=t.w;
    }
  }

  if (DO_QKV) {
    unsigned b = row / (unsigned)NPOS;
    unsigned prow = row - b*(unsigned)NPOS;
    const size_t b4 = (size_t)b*4;
    #pragma unroll
    for (int g = 0; g < 3; ++g) {
      const int cb = 24*s + 8*g;
      float a8[8];
      {
        float4 ba = *(const float4*)(bqkv + cb);
        float4 bb = *(const float4*)(bqkv + cb + 4);
        a8[0]=ba.x; a8[1]=ba.y; a8[2]=ba.z; a8[3]=ba.w;
        a8[4]=bb.x; a8[5]=bb.y; a8[6]=bb.z; a8[7]=bb.w;
      }
      #pragma unroll
      for (int k = 0; k < 32; ++k) {
        float xv = xr[k];
        float4 w0 = *(const float4*)(Wqkv + k*96 + cb);
        float4 w1 = *(const float4*)(Wqkv + k*96 + cb + 4);
        a8[0]+=xv*w0.x; a8[1]+=xv*w0.y; a8[2]+=xv*w0.z; a8[3]+=xv*w0.w;
        a8[4]+=xv*w1.x; a8[5]+=xv*w1.y; a8[6]+=xv*w1.z; a8[7]+=xv*w1.w;
      }
      const int sec = cb >> 5;             // 0=Q 1=K 2=V
      const int hh  = (cb & 31) >> 3;
      const size_t bh = b4 + (size_t)hh;
      if (sec == 0) {
        half8 q;
        #pragma unroll
        for (int j = 0; j < 8; ++j) q[j] = (_Float16)(a8[j]*QSCALE);
        *(half8*)(qkh + (bh*NPOS + prow)*8) = q;
      } else if (sec == 1) {
        half8 kv;
        #pragma unroll
        for (int j = 0; j < 8; ++j) kv[j] = (_Float16)a8[j];
        *(half8*)(kbh + (bh*NPOS + prow)*8) = kv;
      } else {
        #pragma unroll
        for (int j = 0; j < 8; ++j)
          vth[(bh*8 + j)*NPOS + prow] = (_Float16)a8[j];
      }
    }
  }
}

// ------------------------------------------------------------------ attn ----
// Block per (b,h), 512 threads = 8 waves. MFMA 16x16x16 f16. (frozen)
#define KSTR 24
#define VSTR 664
__global__ __launch_bounds__(512) void attn_kernel(
    const _Float16* __restrict__ qkh, const _Float16* __restrict__ kbh,
    const _Float16* __restrict__ vth, float* __restrict__ ob)
{
  __shared__ _Float16 Klds[656*KSTR];
  __shared__ _Float16 VTlds[16*VSTR];
  int bh = blockIdx.x;
  int b = bh >> 2, h = bh & 3;
  int tid = threadIdx.x;
  const half4 z4 = {0,0,0,0};
  for (int r = tid; r < 656; r += 512) {
    half4 a = z4, c = z4;
    if (r < NPOS) {
      a = *(const half4*)(kbh + ((size_t)bh*NPOS + r)*8);
      c = *(const half4*)(kbh + ((size_t)bh*NPOS + r)*8 + 4);
    }
    *(half4*)(Klds + r*KSTR)      = a;
    *(half4*)(Klds + r*KSTR + 4)  = c;
    *(half4*)(Klds + r*KSTR + 8)  = z4;
    *(half4*)(Klds + r*KSTR + 12) = z4;
  }
  for (int c = tid; c < 16*166; c += 512) {
    int d = c / 166, kc = (c % 166)*4;
    half4 v = z4;
    if (d < 8 && kc < 652)
      v = *(const half4*)(vth + ((size_t)bh*8 + d)*NPOS + kc);
    *(half4*)(VTlds + d*VSTR + kc) = v;
  }
  __syncthreads();

  int wave = tid >> 6, lane = tid & 63;
  int q16 = lane & 15;
  int kg  = lane >> 4;
  const float4v zc = {0.f,0.f,0.f,0.f};

  for (int qt = wave; qt < 41; qt += 8) {
    int qrow = qt*16 + q16;
    int qrc = qrow < NPOS ? qrow : NPOS-1;
    half4 qf = z4;
    if (kg < 2)
      qf = *(const half4*)(qkh + ((size_t)bh*NPOS + qrc)*8 + kg*4);
    float4v o = zc;
    float den = 0.f;
    for (int kt = 0; kt < 40; ++kt) {
      half4 kf = *(const half4*)(Klds + (kt*16 + q16)*KSTR + kg*4);
      float4v s = __builtin_amdgcn_mfma_f32_16x16x16f16(kf, qf, zc, 0, 0, 0);
      float p0 = __builtin_amdgcn_exp2f(s[0]);
      float p1 = __builtin_amdgcn_exp2f(s[1]);
      float p2 = __builtin_amdgcn_exp2f(s[2]);
      float p3 = __builtin_amdgcn_exp2f(s[3]);
      den += (p0+p1)+(p2+p3);
      half4 pf; pf[0]=(_Float16)p0; pf[1]=(_Float16)p1; pf[2]=(_Float16)p2; pf[3]=(_Float16)p3;
      half4 vf = *(const half4*)(VTlds + q16*VSTR + kt*16 + kg*4);
      o = __builtin_amdgcn_mfma_f32_16x16x16f16(pf, vf, o, 0, 0, 0);
    }
    {
      half4 kf = *(const half4*)(Klds + (640 + q16)*KSTR + kg*4);
      float4v s = __builtin_amdgcn_mfma_f32_16x16x16f16(kf, qf, zc, 0, 0, 0);
      float p0 = __builtin_amdgcn_exp2f(s[0]);
      float p1 = __builtin_amdgcn_exp2f(s[1]);
      float p2 = __builtin_amdgcn_exp2f(s[2]);
      float p3 = __builtin_amdgcn_exp2f(s[3]);
      if (kg == 3) { p0=0.f; p1=0.f; p2=0.f; p3=0.f; }
      den += (p0+p1)+(p2+p3);
      half4 pf; pf[0]=(_Float16)p0; pf[1]=(_Float16)p1; pf[2]=(_Float16)p2; pf[3]=(_Float16)p3;
      half4 vf = *(const half4*)(VTlds + q16*VSTR + 640 + kg*4);
      o = __builtin_amdgcn_mfma_f32_16x16x16f16(pf, vf, o, 0, 0, 0);
    }
    float den_full = den;
    den_full += __shfl_xor(den_full, 16);
    den_full += __shfl_xor(den_full, 32);
    float dq[4];
    #pragma unroll
    for (int reg = 0; reg < 4; ++reg)
      dq[reg] = __shfl(den_full, 4*kg + reg);
    if (q16 < 8) {
      #pragma unroll
      for (int reg = 0; reg < 4; ++reg) {
        int qo = qt*16 + 4*kg + reg;
        if (qo < NPOS) {
          ob[((size_t)(b*NPOS + qo))*32 + h*8 + q16] = o[reg] / dq[reg];
        }
      }
    }
  }
}

// --------------------------------------------------------------- readout ----
__global__ __launch_bounds__(256) void readout_kernel(
    const float* __restrict__ x,
    const float* __restrict__ Wtraj, const float* __restrict__ btraj,
    const float* __restrict__ Wint, const float* __restrict__ bint,
    float* __restrict__ dout)
{
  int idx = blockIdx.x*256 + threadIdx.x;
  if (idx >= NB*NVEH) return;
  int b = idx >> 6, n = idx & 63;
  int z = n >> 4, v = n & 15;
  int base = 4 + z*ZSTRIDE + 2 + v*10;
  float acc[16];
  #pragma unroll
  for (int i = 0; i < 16; ++i) acc[i] = btraj[i];
  #pragma unroll
  for (int t = 0; t < 4; ++t) {
    const float* xr = x + ((size_t)(b*NPOS + base + 6 + t))*32;
    #pragma unroll
    for (int k = 0; k < 32; ++k) {
      float xv = xr[k];
      const float* wr = Wtraj + (t*32 + k)*16;
      #pragma unroll
      for (int i = 0; i < 16; ++i) acc[i] += xv*wr[i];
    }
  }
  float* to = dout + (size_t)idx*16;
  #pragma unroll
  for (int i = 0; i < 16; ++i) to[i] = acc[i];
  float ai[8];
  #pragma unroll
  for (int j = 0; j < 8; ++j) ai[j] = bint[j];
  #pragma unroll
  for (int t = 0; t < 2; ++t) {
    const float* xr = x + ((size_t)(b*NPOS + base + 4 + t))*32;
    #pragma unroll
    for (int k = 0; k < 32; ++k) {
      float xv = xr[k];
      const float* wr = Wint + (t*32 + k)*8;
      #pragma unroll
      for (int j = 0; j < 8; ++j) ai[j] += xv*wr[j];
    }
  }
  float* io = dout + 131072 + (size_t)idx*8;
  #pragma unroll
  for (int j = 0; j < 8; ++j) io[j] = ai[j];
}

// ---------------------------------------------------------------- launch ----
extern "C" void kernel_launch(void* const* d_in, const int* in_sizes, int n_in,
                              void* d_out, int out_size, void* d_ws, size_t ws_size,
                              hipStream_t stream)
{
  const float* states  = (const float*)d_in[0];
  const float* road_ctx= (const float*)d_in[1];
  const float* pos_emb = (const float*)d_in[2];
  const float* Wp    = (const float*)d_in[4];  const float* bp    = (const float*)d_in[5];
  const float* Wv    = (const float*)d_in[6];  const float* bv    = (const float*)d_in[7];
  const float* Wh    = (const float*)d_in[8];  const float* bh    = (const float*)d_in[9];
  const float* Wc    = (const float*)d_in[10]; const float* bc    = (const float*)d_in[11];
  const float* Wflow = (const float*)d_in[12]; const float* bflow = (const float*)d_in[13];
  const float* Wsig  = (const float*)d_in[14]; const float* bsig  = (const float*)d_in[15];
  const float* Wtraj = (const float*)d_in[16]; const float* btraj = (const float*)d_in[17];
  const float* Wint  = (const float*)d_in[18]; const float* bint  = (const float*)d_in[19];
  const float* Wqkv  = (const float*)d_in[20]; const float* bqkv  = (const float*)d_in[21];
  const float* Wo    = (const float*)d_in[22]; const float* bo    = (const float*)d_in[23];
  const float* g1    = (const float*)d_in[24]; const float* b1ln  = (const float*)d_in[25];
  const float* W1    = (const float*)d_in[26]; const float* b1    = (const float*)d_in[27];
  const float* W2    = (const float*)d_in[28]; const float* b2    = (const float*)d_in[29];
  const float* g2    = (const float*)d_in[30]; const float* b2ln  = (const float*)d_in[31];

  float* x  = (float*)d_ws;
  float* ob = x + (size_t)MROWS*32;
  _Float16* qkh = (_Float16*)(ob + (size_t)MROWS*32);
  _Float16* kbh = qkh + (size_t)512*NPOS*8;
  _Float16* vth = kbh + (size_t)512*NPOS*8;

  canvas_kernel<<<NB, 256, 0, stream>>>(states, road_ctx, pos_emb,
      Wp, bp, Wv, bv, Wh, bh, Wc, bc, Wflow, bflow, Wsig, bsig, x);

  const int rowBlocks = MROWS/64;   // 1304

  // layer 0 QKV
  slice_kernel<false,true><<<rowBlocks, 256, 0, stream>>>(
      nullptr, x, nullptr,
      nullptr, nullptr, nullptr, nullptr,
      nullptr, nullptr, nullptr, nullptr, nullptr, nullptr,
      Wqkv, bqkv, qkh, kbh, vth);

  attn_kernel<<<NB*NH, 512, 0, stream>>>(qkh, kbh, vth, ob);

  // layer 0 proj+LN+FFN+LN fused with layer 1 QKV
  slice_kernel<true,true><<<rowBlocks, 256, 0, stream>>>(
      ob, x, x,
      Wo, bo, g1, b1ln,
      W1, b1, W2, b2, g2, b2ln,
      Wqkv + 32*96, bqkv + 96, qkh, kbh, vth);

  attn_kernel<<<NB*NH, 512, 0, stream>>>(qkh, kbh, vth, ob);

  // layer 1 proj+LN+FFN+LN
  slice_kernel<true,false><<<rowBlocks, 256, 0, stream>>>(
      ob, x, x,
      Wo + 32*32, bo + 32, g1 + 32, b1ln + 32,
      W1 + 32*128, b1 + 128, W2 + 128*32, b2 + 32, g2 + 32, b2ln + 32,
      nullptr, nullptr, nullptr, nullptr, nullptr);

  readout_kernel<<<(NB*NVEH + 255)/256, 256, 0, stream>>>(
      x, Wtraj, btraj, Wint, bint, (float*)d_out);
}

// Round 9
// 184.490 us; speedup vs baseline: 5.0830x; 5.0830x over previous
//
#include <hip/hip_runtime.h>
#include <hip/hip_bf16.h>
#include <math.h>

// FleetModel forward. Round 9: round-8 MFMA engine with the layer-plumbing
// fix — engine takes SEPARATE packed-weight bases for proj/FFN (layer L)
// and qkv (layer L+1). Round-8 bug: fused engine used layer-0 qkv weights
// with layer-1 qkv biases.
#define NB 128
#define NPOS 652
#define DD 32
#define NH 4
#define NVEH 64
#define ZSTRIDE 162          // 2 + 16*10
#define MROWS (NB*NPOS)      // 83456 = 1304 * 64
#define QSCALE 0.51011784f   // (1/sqrt(8)) * log2(e)

// packed-weight region offsets (f16 elements, per layer)
#define PACK_WO 0
#define PACK_W1 1024
#define PACK_W2 5120
#define PACK_WQ 9216
#define PACK_LAYER 12288

typedef _Float16 half4 __attribute__((ext_vector_type(4)));
typedef _Float16 half8 __attribute__((ext_vector_type(8)));
typedef float float4v __attribute__((ext_vector_type(4)));

__device__ __forceinline__ float4v mfma16(half4 a, half4 b, float4v c) {
  return __builtin_amdgcn_mfma_f32_16x16x16f16(a, b, c, 0, 0, 0);
}

__device__ __forceinline__ float wave_sum64(float v) {
  #pragma unroll
  for (int off = 32; off > 0; off >>= 1) v += __shfl_down(v, off);
  return v;
}

// ---------------------------------------------------------------- canvas ----
__global__ __launch_bounds__(256) void canvas_kernel(
    const float* __restrict__ states, const float* __restrict__ road_ctx,
    const float* __restrict__ pos_emb,
    const float* __restrict__ Wp, const float* __restrict__ bp,
    const float* __restrict__ Wv, const float* __restrict__ bv,
    const float* __restrict__ Wh, const float* __restrict__ bh,
    const float* __restrict__ Wc, const float* __restrict__ bc,
    const float* __restrict__ Wflow, const float* __restrict__ bflow,
    const float* __restrict__ Wsig, const float* __restrict__ bsig,
    float* __restrict__ x, _Float16* __restrict__ xh)
{
  int b = blockIdx.x;
  int tid = threadIdx.x;
  __shared__ float mvs[2];
  if (tid < 64) {
    float vx = states[(b*NVEH + tid)*4 + 2];
    float vy = states[(b*NVEH + tid)*4 + 3];
    vx = wave_sum64(vx); vy = wave_sum64(vy);
    if (tid == 0) { mvs[0] = vx * (1.f/64.f); mvs[1] = vy * (1.f/64.f); }
  }
  __syncthreads();
  float mv0 = mvs[0], mv1 = mvs[1];
  for (int i = tid; i < NPOS*DD; i += 256) {
    int p = i >> 5, d = i & 31;
    float val = pos_emb[i];
    if (p < 4) {
      val += mv0*Wflow[p*32 + d] + mv1*Wflow[128 + p*32 + d] + bflow[p*32 + d];
    } else {
      int q = p - 4, z = q / ZSTRIDE, r = q % ZSTRIDE;
      if (r == 0) {
        val += Wsig[d] + bsig[d];
      } else if (r >= 2) {
        int vr = r - 2, v = vr / 10, s = vr % 10;
        int n = z*16 + v;
        const float* st = states + (b*NVEH + n)*4;
        if (s == 0) {
          val += st[0]*Wp[d] + st[1]*Wp[32+d] + bp[d];
        } else if (s == 1) {
          val += st[2]*Wv[d] + st[3]*Wv[32+d] + bv[d];
        } else if (s == 2) {
          float sp = fmaxf(sqrtf(st[2]*st[2] + st[3]*st[3]), 0.1f);
          val += (st[2]/sp)*Wh[d] + (st[3]/sp)*Wh[32+d] + bh[d];
        } else if (s == 3) {
          const float* rc = road_ctx + (b*NVEH + n)*4;
          val += rc[0]*Wc[d] + rc[1]*Wc[32+d] + rc[2]*Wc[64+d] + rc[3]*Wc[96+d] + bc[d];
        }
      }
    }
    x[(size_t)b*NPOS*DD + i] = val;
    xh[(size_t)b*NPOS*DD + i] = (_Float16)val;
  }
}

// ------------------------------------------------------------------ pack ----
__global__ void pack_kernel(const float* __restrict__ Wqkv,
                            const float* __restrict__ Wo,
                            const float* __restrict__ W1,
                            const float* __restrict__ W2,
                            _Float16* __restrict__ P)
{
  int L = blockIdx.x;
  int l = threadIdx.x;            // 0..63
  int c = l & 15, g = l >> 4;
  _Float16* PL = P + L*PACK_LAYER;
  const float* WoL = Wo   + L*32*32;
  const float* W1L = W1   + L*32*128;
  const float* W2L = W2   + L*128*32;
  const float* WqL = Wqkv + L*32*96;
  for (int t = 0; t < 2; ++t)
    for (int kp = 0; kp < 2; ++kp)
      for (int jj = 0; jj < 4; ++jj)
        PL[PACK_WO + ((t*2+kp)*64 + l)*4 + jj] =
            (_Float16)WoL[(kp*16 + 4*g + jj)*32 + t*16 + c];
  for (int t = 0; t < 8; ++t)
    for (int kp = 0; kp < 2; ++kp)
      for (int jj = 0; jj < 4; ++jj)
        PL[PACK_W1 + ((t*2+kp)*64 + l)*4 + jj] =
            (_Float16)W1L[(kp*16 + 4*g + jj)*128 + t*16 + c];
  for (int t = 0; t < 2; ++t)
    for (int kp = 0; kp < 8; ++kp)
      for (int jj = 0; jj < 4; ++jj)
        PL[PACK_W2 + ((t*8+kp)*64 + l)*4 + jj] =
            (_Float16)W2L[(kp*16 + 4*g + jj)*32 + t*16 + c];
  for (int t = 0; t < 6; ++t)
    for (int kp = 0; kp < 2; ++kp)
      for (int jj = 0; jj < 4; ++jj) {
        float v = WqL[(kp*16 + 4*g + jj)*96 + t*16 + c];
        if (t < 2) v *= QSCALE;   // fold softmax scale*log2e into Q weights
        PL[PACK_WQ + ((t*2+kp)*64 + l)*4 + jj] = (_Float16)v;
      }
}

// ---------------------------------------------------------------- engine ----
// Fused per-layer row engine on MFMA. Block = 256 thr = 4 waves; wave w owns
// rows r0 = blk*64 + w*16. Wave-private LDS, no barriers.
// Pm: packed proj/FFN weights (layer L). Pq: packed qkv weights (layer for
// the NEXT attention). mfma conventions verified by the passing attn kernel.
template<bool DO_PROJ, bool DO_QKV>
__global__ __launch_bounds__(256) void engine_kernel(
    const _Float16* __restrict__ oh,   // attn out f16 (proj input)
    const _Float16* __restrict__ xh,   // x f16 (qkv input when !DO_PROJ)
    float* xf,                         // fp32 resid master (in/out, own rows)
    const _Float16* __restrict__ Pm,   // proj/FFN packed weights
    const _Float16* __restrict__ Pq,   // qkv packed weights
    const float* __restrict__ bo,
    const float* __restrict__ g1v, const float* __restrict__ b1v,
    const float* __restrict__ b1f, const float* __restrict__ b2f,
    const float* __restrict__ g2v, const float* __restrict__ b2v,
    const float* __restrict__ bqkv,
    _Float16* __restrict__ qkh, _Float16* __restrict__ kbh,
    _Float16* __restrict__ vth)
{
  __shared__ _Float16 yls[4][16][36];    // wave-private transpose buffers
  __shared__ _Float16 hls[4][16][132];
  const int tid = threadIdx.x;
  const int w = tid >> 6, l = tid & 63;
  const int c = l & 15, g = l >> 4;
  const int r0 = blockIdx.x*64 + w*16;
  const float4v zc = {0.f,0.f,0.f,0.f};

  half4 ax_lo, ax_hi;    // A-frag of new x for qkv

  if (DO_PROJ) {
    // ---- proj: t = oh @ Wo  (N=32: 2 tiles, K=32: 2 frags)
    half4 a_lo = *(const half4*)(oh + (size_t)(r0 + c)*32 + 4*g);
    half4 a_hi = *(const half4*)(oh + (size_t)(r0 + c)*32 + 16 + 4*g);
    float4v c0 = mfma16(a_lo, *(const half4*)(Pm + PACK_WO + (0*64+l)*4), zc);
    c0 = mfma16(a_hi, *(const half4*)(Pm + PACK_WO + (1*64+l)*4), c0);
    float4v c1 = mfma16(a_lo, *(const half4*)(Pm + PACK_WO + (2*64+l)*4), zc);
    c1 = mfma16(a_hi, *(const half4*)(Pm + PACK_WO + (3*64+l)*4), c1);
    // ---- + bo + resid
    float boc0 = bo[c], boc1 = bo[c+16];
    float t0[4], t1[4];
    #pragma unroll
    for (int reg = 0; reg < 4; ++reg) {
      size_t Rd = (size_t)(r0 + 4*g + reg);
      t0[reg] = c0[reg] + boc0 + xf[Rd*32 + c];
      t1[reg] = c1[reg] + boc1 + xf[Rd*32 + c + 16];
    }
    // ---- LN1 (reduce over the 16 lanes sharing g = same rows)
    float g1c0 = g1v[c], g1c1 = g1v[c+16], b1c0 = b1v[c], b1c1 = b1v[c+16];
    float y0[4], y1[4];
    #pragma unroll
    for (int reg = 0; reg < 4; ++reg) {
      float s1 = t0[reg] + t1[reg];
      float s2 = t0[reg]*t0[reg] + t1[reg]*t1[reg];
      s1 += __shfl_xor(s1, 1); s1 += __shfl_xor(s1, 2);
      s1 += __shfl_xor(s1, 4); s1 += __shfl_xor(s1, 8);
      s2 += __shfl_xor(s2, 1); s2 += __shfl_xor(s2, 2);
      s2 += __shfl_xor(s2, 4); s2 += __shfl_xor(s2, 8);
      float m = s1*(1.f/32.f);
      float rv = rsqrtf(s2*(1.f/32.f) - m*m + 1e-5f);
      y0[reg] = (t0[reg]-m)*rv*g1c0 + b1c0;
      y1[reg] = (t1[reg]-m)*rv*g1c1 + b1c1;
    }
    // ---- transpose y (D layout -> A-frag layout) via wave-private LDS
    #pragma unroll
    for (int reg = 0; reg < 4; ++reg) {
      yls[w][4*g+reg][c]      = (_Float16)y0[reg];
      yls[w][4*g+reg][c + 16] = (_Float16)y1[reg];
    }
    half4 ay_lo = *(const half4*)&yls[w][c][4*g];
    half4 ay_hi = *(const half4*)&yls[w][c][16 + 4*g];
    // ---- FFN1: h = relu(y@W1 + b1)  (8 tiles) -> transpose into hls
    #pragma unroll
    for (int t = 0; t < 8; ++t) {
      float4v hc = mfma16(ay_lo, *(const half4*)(Pm + PACK_W1 + ((t*2+0)*64+l)*4), zc);
      hc = mfma16(ay_hi, *(const half4*)(Pm + PACK_W1 + ((t*2+1)*64+l)*4), hc);
      float bb = b1f[t*16 + c];
      #pragma unroll
      for (int reg = 0; reg < 4; ++reg)
        hls[w][4*g+reg][t*16 + c] = (_Float16)fmaxf(hc[reg] + bb, 0.f);
    }
    // ---- FFN2: z = h@W2  (N=32: 2 tiles, K=128: 8 frags)
    float4v z0 = zc, z1 = zc;
    #pragma unroll
    for (int kp = 0; kp < 8; ++kp) {
      half4 ah = *(const half4*)&hls[w][c][kp*16 + 4*g];
      z0 = mfma16(ah, *(const half4*)(Pm + PACK_W2 + ((0*8+kp)*64+l)*4), z0);
      z1 = mfma16(ah, *(const half4*)(Pm + PACK_W2 + ((1*8+kp)*64+l)*4), z1);
    }
    // ---- + b2 + y resid + LN2 -> new x
    float b2c0 = b2f[c], b2c1 = b2f[c+16];
    float g2c0 = g2v[c], g2c1 = g2v[c+16], bt0 = b2v[c], bt1 = b2v[c+16];
    float xn0[4], xn1[4];
    #pragma unroll
    for (int reg = 0; reg < 4; ++reg) {
      float u0 = z0[reg] + b2c0 + y0[reg];
      float u1 = z1[reg] + b2c1 + y1[reg];
      float s1 = u0 + u1;
      float s2 = u0*u0 + u1*u1;
      s1 += __shfl_xor(s1, 1); s1 += __shfl_xor(s1, 2);
      s1 += __shfl_xor(s1, 4); s1 += __shfl_xor(s1, 8);
      s2 += __shfl_xor(s2, 1); s2 += __shfl_xor(s2, 2);
      s2 += __shfl_xor(s2, 4); s2 += __shfl_xor(s2, 8);
      float m = s1*(1.f/32.f);
      float rv = rsqrtf(s2*(1.f/32.f) - m*m + 1e-5f);
      xn0[reg] = (u0-m)*rv*g2c0 + bt0;
      xn1[reg] = (u1-m)*rv*g2c1 + bt1;
    }
    // ---- store fp32 x
    #pragma unroll
    for (int reg = 0; reg < 4; ++reg) {
      size_t Rd = (size_t)(r0 + 4*g + reg);
      xf[Rd*32 + c]      = xn0[reg];
      xf[Rd*32 + c + 16] = xn1[reg];
    }
    if (DO_QKV) {   // transpose new x into A-frags (reuse yls)
      #pragma unroll
      for (int reg = 0; reg < 4; ++reg) {
        yls[w][4*g+reg][c]      = (_Float16)xn0[reg];
        yls[w][4*g+reg][c + 16] = (_Float16)xn1[reg];
      }
      ax_lo = *(const half4*)&yls[w][c][4*g];
      ax_hi = *(const half4*)&yls[w][c][16 + 4*g];
    }
  } else if (DO_QKV) {
    ax_lo = *(const half4*)(xh + (size_t)(r0 + c)*32 + 4*g);
    ax_hi = *(const half4*)(xh + (size_t)(r0 + c)*32 + 16 + 4*g);
  }

  if (DO_QKV) {
    #pragma unroll
    for (int t = 0; t < 6; ++t) {     // 6 col tiles over qkv's 96 cols
      float4v qc = mfma16(ax_lo, *(const half4*)(Pq + PACK_WQ + ((t*2+0)*64+l)*4), zc);
      qc = mfma16(ax_hi, *(const half4*)(Pq + PACK_WQ + ((t*2+1)*64+l)*4), qc);
      const int colg = t*16 + c;                  // global qkv col 0..95
      float bb = bqkv[colg] * ((t < 2) ? QSCALE : 1.f);
      const int sec = t >> 1;                     // 0=Q 1=K 2=V (tile-uniform)
      const int hh = (colg & 31) >> 3, dd = colg & 7;
      #pragma unroll
      for (int reg = 0; reg < 4; ++reg) {
        unsigned Rd = (unsigned)(r0 + 4*g + reg);
        unsigned bI = Rd / 652u;
        unsigned p  = Rd - bI*652u;
        _Float16 v = (_Float16)(qc[reg] + bb);
        if (sec == 0)      qkh[((size_t)(bI*4+hh)*NPOS + p)*8 + dd] = v;
        else if (sec == 1) kbh[((size_t)(bI*4+hh)*NPOS + p)*8 + dd] = v;
        else               vth[((size_t)(bI*4+hh)*8 + dd)*NPOS + p] = v;
      }
    }
  }
}

// ------------------------------------------------------------------ attn ----
// Block per (b,h), 512 threads = 8 waves. MFMA 16x16x16 f16. Output -> f16.
#define KSTR 24
#define VSTR 664
__global__ __launch_bounds__(512) void attn_kernel(
    const _Float16* __restrict__ qkh, const _Float16* __restrict__ kbh,
    const _Float16* __restrict__ vth, _Float16* __restrict__ oh)
{
  __shared__ _Float16 Klds[656*KSTR];
  __shared__ _Float16 VTlds[16*VSTR];
  int bh = blockIdx.x;
  int b = bh >> 2, h = bh & 3;
  int tid = threadIdx.x;
  const half4 z4 = {0,0,0,0};
  for (int r = tid; r < 656; r += 512) {
    half4 a = z4, c = z4;
    if (r < NPOS) {
      a = *(const half4*)(kbh + ((size_t)bh*NPOS + r)*8);
      c = *(const half4*)(kbh + ((size_t)bh*NPOS + r)*8 + 4);
    }
    *(half4*)(Klds + r*KSTR)      = a;
    *(half4*)(Klds + r*KSTR + 4)  = c;
    *(half4*)(Klds + r*KSTR + 8)  = z4;
    *(half4*)(Klds + r*KSTR + 12) = z4;
  }
  for (int c = tid; c < 16*166; c += 512) {
    int d = c / 166, kc = (c % 166)*4;
    half4 v = z4;
    if (d < 8 && kc < 652)
      v = *(const half4*)(vth + ((size_t)bh*8 + d)*NPOS + kc);
    *(half4*)(VTlds + d*VSTR + kc) = v;
  }
  __syncthreads();

  int wave = tid >> 6, lane = tid & 63;
  int q16 = lane & 15;
  int kg  = lane >> 4;
  const float4v zc = {0.f,0.f,0.f,0.f};

  for (int qt = wave; qt < 41; qt += 8) {
    int qrow = qt*16 + q16;
    int qrc = qrow < NPOS ? qrow : NPOS-1;
    half4 qf = z4;
    if (kg < 2)
      qf = *(const half4*)(qkh + ((size_t)bh*NPOS + qrc)*8 + kg*4);
    float4v o = zc;
    float den = 0.f;
    for (int kt = 0; kt < 40; ++kt) {
      half4 kf = *(const half4*)(Klds + (kt*16 + q16)*KSTR + kg*4);
      float4v s = __builtin_amdgcn_mfma_f32_16x16x16f16(kf, qf, zc, 0, 0, 0);
      float p0 = __builtin_amdgcn_exp2f(s[0]);
      float p1 = __builtin_amdgcn_exp2f(s[1]);
      float p2 = __builtin_amdgcn_exp2f(s[2]);
      float p3 = __builtin_amdgcn_exp2f(s[3]);
      den += (p0+p1)+(p2+p3);
      half4 pf; pf[0]=(_Float16)p0; pf[1]=(_Float16)p1; pf[2]=(_Float16)p2; pf[3]=(_Float16)p3;
      half4 vf = *(const half4*)(VTlds + q16*VSTR + kt*16 + kg*4);
      o = __builtin_amdgcn_mfma_f32_16x16x16f16(pf, vf, o, 0, 0, 0);
    }
    {
      half4 kf = *(const half4*)(Klds + (640 + q16)*KSTR + kg*4);
      float4v s = __builtin_amdgcn_mfma_f32_16x16x16f16(kf, qf, zc, 0, 0, 0);
      float p0 = __builtin_amdgcn_exp2f(s[0]);
      float p1 = __builtin_amdgcn_exp2f(s[1]);
      float p2 = __builtin_amdgcn_exp2f(s[2]);
      float p3 = __builtin_amdgcn_exp2f(s[3]);
      if (kg == 3) { p0=0.f; p1=0.f; p2=0.f; p3=0.f; }
      den += (p0+p1)+(p2+p3);
      half4 pf; pf[0]=(_Float16)p0; pf[1]=(_Float16)p1; pf[2]=(_Float16)p2; pf[3]=(_Float16)p3;
      half4 vf = *(const half4*)(VTlds + q16*VSTR + 640 + kg*4);
      o = __builtin_amdgcn_mfma_f32_16x16x16f16(pf, vf, o, 0, 0, 0);
    }
    float den_full = den;
    den_full += __shfl_xor(den_full, 16);
    den_full += __shfl_xor(den_full, 32);
    float dq[4];
    #pragma unroll
    for (int reg = 0; reg < 4; ++reg)
      dq[reg] = __shfl(den_full, 4*kg + reg);
    if (q16 < 8) {
      #pragma unroll
      for (int reg = 0; reg < 4; ++reg) {
        int qo = qt*16 + 4*kg + reg;
        if (qo < NPOS) {
          oh[((size_t)(b*NPOS + qo))*32 + h*8 + q16] = (_Float16)(o[reg] / dq[reg]);
        }
      }
    }
  }
}

// --------------------------------------------------------------- readout ----
__global__ __launch_bounds__(256) void readout_kernel(
    const float* __restrict__ x,
    const float* __restrict__ Wtraj, const float* __restrict__ btraj,
    const float* __restrict__ Wint, const float* __restrict__ bint,
    float* __restrict__ dout)
{
  int idx = blockIdx.x*256 + threadIdx.x;
  if (idx >= NB*NVEH) return;
  int b = idx >> 6, n = idx & 63;
  int z = n >> 4, v = n & 15;
  int base = 4 + z*ZSTRIDE + 2 + v*10;
  float acc[16];
  #pragma unroll
  for (int i = 0; i < 16; ++i) acc[i] = btraj[i];
  #pragma unroll
  for (int t = 0; t < 4; ++t) {
    const float* xr = x + ((size_t)(b*NPOS + base + 6 + t))*32;
    #pragma unroll
    for (int k = 0; k < 32; ++k) {
      float xv = xr[k];
      const float* wr = Wtraj + (t*32 + k)*16;
      #pragma unroll
      for (int i = 0; i < 16; ++i) acc[i] += xv*wr[i];
    }
  }
  float* to = dout + (size_t)idx*16;
  #pragma unroll
  for (int i = 0; i < 16; ++i) to[i] = acc[i];
  float ai[8];
  #pragma unroll
  for (int j = 0; j < 8; ++j) ai[j] = bint[j];
  #pragma unroll
  for (int t = 0; t < 2; ++t) {
    const float* xr = x + ((size_t)(b*NPOS + base + 4 + t))*32;
    #pragma unroll
    for (int k = 0; k < 32; ++k) {
      float xv = xr[k];
      const float* wr = Wint + (t*32 + k)*8;
      #pragma unroll
      for (int j = 0; j < 8; ++j) ai[j] += xv*wr[j];
    }
  }
  float* io = dout + 131072 + (size_t)idx*8;
  #pragma unroll
  for (int j = 0; j < 8; ++j) io[j] = ai[j];
}

// ---------------------------------------------------------------- launch ----
extern "C" void kernel_launch(void* const* d_in, const int* in_sizes, int n_in,
                              void* d_out, int out_size, void* d_ws, size_t ws_size,
                              hipStream_t stream)
{
  const float* states  = (const float*)d_in[0];
  const float* road_ctx= (const float*)d_in[1];
  const float* pos_emb = (const float*)d_in[2];
  const float* Wp    = (const float*)d_in[4];  const float* bp    = (const float*)d_in[5];
  const float* Wv    = (const float*)d_in[6];  const float* bv    = (const float*)d_in[7];
  const float* Wh    = (const float*)d_in[8];  const float* bh    = (const float*)d_in[9];
  const float* Wc    = (const float*)d_in[10]; const float* bc    = (const float*)d_in[11];
  const float* Wflow = (const float*)d_in[12]; const float* bflow = (const float*)d_in[13];
  const float* Wsig  = (const float*)d_in[14]; const float* bsig  = (const float*)d_in[15];
  const float* Wtraj = (const float*)d_in[16]; const float* btraj = (const float*)d_in[17];
  const float* Wint  = (const float*)d_in[18]; const float* bint  = (const float*)d_in[19];
  const float* Wqkv  = (const float*)d_in[20]; const float* bqkv  = (const float*)d_in[21];
  const float* Wo    = (const float*)d_in[22]; const float* bo    = (const float*)d_in[23];
  const float* g1    = (const float*)d_in[24]; const float* b1ln  = (const float*)d_in[25];
  const float* W1    = (const float*)d_in[26]; const float* b1    = (const float*)d_in[27];
  const float* W2    = (const float*)d_in[28]; const float* b2    = (const float*)d_in[29];
  const float* g2    = (const float*)d_in[30]; const float* b2ln  = (const float*)d_in[31];

  // workspace layout
  float*     xf  = (float*)d_ws;                           // 10.7 MB fp32
  _Float16*  oh  = (_Float16*)(xf + (size_t)MROWS*32);     // 5.3 MB f16
  _Float16*  xh  = oh  + (size_t)MROWS*32;                 // 5.3 MB f16
  _Float16*  qkh = xh  + (size_t)MROWS*32;                 // 5.3 MB
  _Float16*  kbh = qkh + (size_t)512*NPOS*8;               // 5.3 MB
  _Float16*  vth = kbh + (size_t)512*NPOS*8;               // 5.3 MB
  _Float16*  P   = vth + (size_t)512*NPOS*8;               // 48 KB packed W

  canvas_kernel<<<NB, 256, 0, stream>>>(states, road_ctx, pos_emb,
      Wp, bp, Wv, bv, Wh, bh, Wc, bc, Wflow, bflow, Wsig, bsig, xf, xh);

  pack_kernel<<<2, 64, 0, stream>>>(Wqkv, Wo, W1, W2, P);

  const int eBlocks = MROWS/64;   // 1304

  // layer 0 qkv (from canvas xh; qkv weights layer 0)
  engine_kernel<false,true><<<eBlocks, 256, 0, stream>>>(
      nullptr, xh, xf, nullptr, P,
      nullptr, nullptr, nullptr, nullptr, nullptr, nullptr, nullptr,
      bqkv, qkh, kbh, vth);

  attn_kernel<<<NB*NH, 512, 0, stream>>>(qkh, kbh, vth, oh);

  // layer 0 proj+LN+FFN+LN (Pm = layer 0) fused with layer 1 qkv (Pq = layer 1)
  engine_kernel<true,true><<<eBlocks, 256, 0, stream>>>(
      oh, nullptr, xf, P, P + PACK_LAYER,
      bo, g1, b1ln, b1, b2, g2, b2ln,
      bqkv + 96, qkh, kbh, vth);

  attn_kernel<<<NB*NH, 512, 0, stream>>>(qkh, kbh, vth, oh);

  // layer 1 proj+LN+FFN+LN (Pm = layer 1)
  engine_kernel<true,false><<<eBlocks, 256, 0, stream>>>(
      oh, nullptr, xf, P + PACK_LAYER, nullptr,
      bo + 32, g1 + 32, b1ln + 32, b1 + 128, b2 + 32, g2 + 32, b2ln + 32,
      nullptr, nullptr, nullptr, nullptr);

  readout_kernel<<<(NB*NVEH + 255)/256, 256, 0, stream>>>(
      xf, Wtraj, btraj, Wint, bint, (float*)d_out);
}

// Round 10
// 160.911 us; speedup vs baseline: 5.8279x; 1.1465x over previous
//
#include <hip/hip_runtime.h>
#include <hip/hip_bf16.h>
#include <math.h>

// FleetModel forward. Round 10: canvas widened to 1024 blocks; attn gets
// bank-conflict-free swizzled K LDS, VSTR=668, and free denominator via a
// ones-row in V^T (slot d=8), removing the masked tail + den reduction.
#define NB 128
#define NPOS 652
#define DD 32
#define NH 4
#define NVEH 64
#define ZSTRIDE 162          // 2 + 16*10
#define MROWS (NB*NPOS)      // 83456 = 1304 * 64
#define QSCALE 0.51011784f   // (1/sqrt(8)) * log2(e)

// packed-weight region offsets (f16 elements, per layer)
#define PACK_WO 0
#define PACK_W1 1024
#define PACK_W2 5120
#define PACK_WQ 9216
#define PACK_LAYER 12288

typedef _Float16 half4 __attribute__((ext_vector_type(4)));
typedef _Float16 half8 __attribute__((ext_vector_type(8)));
typedef float float4v __attribute__((ext_vector_type(4)));

__device__ __forceinline__ float4v mfma16(half4 a, half4 b, float4v c) {
  return __builtin_amdgcn_mfma_f32_16x16x16f16(a, b, c, 0, 0, 0);
}

__device__ __forceinline__ float wave_sum64(float v) {
  #pragma unroll
  for (int off = 32; off > 0; off >>= 1) v += __shfl_down(v, off);
  return v;
}

// ---------------------------------------------------------------- canvas ----
// 8 chunks per batch -> 1024 blocks (round-9: 128 blocks = 4.8% occupancy).
__global__ __launch_bounds__(256) void canvas_kernel(
    const float* __restrict__ states, const float* __restrict__ road_ctx,
    const float* __restrict__ pos_emb,
    const float* __restrict__ Wp, const float* __restrict__ bp,
    const float* __restrict__ Wv, const float* __restrict__ bv,
    const float* __restrict__ Wh, const float* __restrict__ bh,
    const float* __restrict__ Wc, const float* __restrict__ bc,
    const float* __restrict__ Wflow, const float* __restrict__ bflow,
    const float* __restrict__ Wsig, const float* __restrict__ bsig,
    float* __restrict__ x, _Float16* __restrict__ xh)
{
  int blk = blockIdx.x;
  int b = blk >> 3, chunk = blk & 7;
  int tid = threadIdx.x;
  __shared__ float mvs[2];
  if (tid < 64) {
    float vx = states[(b*NVEH + tid)*4 + 2];
    float vy = states[(b*NVEH + tid)*4 + 3];
    vx = wave_sum64(vx); vy = wave_sum64(vy);
    if (tid == 0) { mvs[0] = vx * (1.f/64.f); mvs[1] = vy * (1.f/64.f); }
  }
  __syncthreads();
  float mv0 = mvs[0], mv1 = mvs[1];
  const int i0 = chunk*2608, i1 = i0 + 2608;   // 2608 = 652*32/8
  for (int i = i0 + tid; i < i1; i += 256) {
    int p = i >> 5, d = i & 31;
    float val = pos_emb[i];
    if (p < 4) {
      val += mv0*Wflow[p*32 + d] + mv1*Wflow[128 + p*32 + d] + bflow[p*32 + d];
    } else {
      int q = p - 4, z = q / ZSTRIDE, r = q % ZSTRIDE;
      if (r == 0) {
        val += Wsig[d] + bsig[d];
      } else if (r >= 2) {
        int vr = r - 2, v = vr / 10, s = vr % 10;
        int n = z*16 + v;
        const float* st = states + (b*NVEH + n)*4;
        if (s == 0) {
          val += st[0]*Wp[d] + st[1]*Wp[32+d] + bp[d];
        } else if (s == 1) {
          val += st[2]*Wv[d] + st[3]*Wv[32+d] + bv[d];
        } else if (s == 2) {
          float sp = fmaxf(sqrtf(st[2]*st[2] + st[3]*st[3]), 0.1f);
          val += (st[2]/sp)*Wh[d] + (st[3]/sp)*Wh[32+d] + bh[d];
        } else if (s == 3) {
          const float* rc = road_ctx + (b*NVEH + n)*4;
          val += rc[0]*Wc[d] + rc[1]*Wc[32+d] + rc[2]*Wc[64+d] + rc[3]*Wc[96+d] + bc[d];
        }
      }
    }
    x[(size_t)b*NPOS*DD + i] = val;
    xh[(size_t)b*NPOS*DD + i] = (_Float16)val;
  }
}

// ------------------------------------------------------------------ pack ----
__global__ void pack_kernel(const float* __restrict__ Wqkv,
                            const float* __restrict__ Wo,
                            const float* __restrict__ W1,
                            const float* __restrict__ W2,
                            _Float16* __restrict__ P)
{
  int L = blockIdx.x;
  int l = threadIdx.x;            // 0..63
  int c = l & 15, g = l >> 4;
  _Float16* PL = P + L*PACK_LAYER;
  const float* WoL = Wo   + L*32*32;
  const float* W1L = W1   + L*32*128;
  const float* W2L = W2   + L*128*32;
  const float* WqL = Wqkv + L*32*96;
  for (int t = 0; t < 2; ++t)
    for (int kp = 0; kp < 2; ++kp)
      for (int jj = 0; jj < 4; ++jj)
        PL[PACK_WO + ((t*2+kp)*64 + l)*4 + jj] =
            (_Float16)WoL[(kp*16 + 4*g + jj)*32 + t*16 + c];
  for (int t = 0; t < 8; ++t)
    for (int kp = 0; kp < 2; ++kp)
      for (int jj = 0; jj < 4; ++jj)
        PL[PACK_W1 + ((t*2+kp)*64 + l)*4 + jj] =
            (_Float16)W1L[(kp*16 + 4*g + jj)*128 + t*16 + c];
  for (int t = 0; t < 2; ++t)
    for (int kp = 0; kp < 8; ++kp)
      for (int jj = 0; jj < 4; ++jj)
        PL[PACK_W2 + ((t*8+kp)*64 + l)*4 + jj] =
            (_Float16)W2L[(kp*16 + 4*g + jj)*32 + t*16 + c];
  for (int t = 0; t < 6; ++t)
    for (int kp = 0; kp < 2; ++kp)
      for (int jj = 0; jj < 4; ++jj) {
        float v = WqL[(kp*16 + 4*g + jj)*96 + t*16 + c];
        if (t < 2) v *= QSCALE;   // fold softmax scale*log2e into Q weights
        PL[PACK_WQ + ((t*2+kp)*64 + l)*4 + jj] = (_Float16)v;
      }
}

// ---------------------------------------------------------------- engine ----
// (unchanged from round 9 — passing, ~15 µs/dispatch)
template<bool DO_PROJ, bool DO_QKV>
__global__ __launch_bounds__(256) void engine_kernel(
    const _Float16* __restrict__ oh,
    const _Float16* __restrict__ xh,
    float* xf,
    const _Float16* __restrict__ Pm,
    const _Float16* __restrict__ Pq,
    const float* __restrict__ bo,
    const float* __restrict__ g1v, const float* __restrict__ b1v,
    const float* __restrict__ b1f, const float* __restrict__ b2f,
    const float* __restrict__ g2v, const float* __restrict__ b2v,
    const float* __restrict__ bqkv,
    _Float16* __restrict__ qkh, _Float16* __restrict__ kbh,
    _Float16* __restrict__ vth)
{
  __shared__ _Float16 yls[4][16][36];
  __shared__ _Float16 hls[4][16][132];
  const int tid = threadIdx.x;
  const int w = tid >> 6, l = tid & 63;
  const int c = l & 15, g = l >> 4;
  const int r0 = blockIdx.x*64 + w*16;
  const float4v zc = {0.f,0.f,0.f,0.f};

  half4 ax_lo, ax_hi;

  if (DO_PROJ) {
    half4 a_lo = *(const half4*)(oh + (size_t)(r0 + c)*32 + 4*g);
    half4 a_hi = *(const half4*)(oh + (size_t)(r0 + c)*32 + 16 + 4*g);
    float4v c0 = mfma16(a_lo, *(const half4*)(Pm + PACK_WO + (0*64+l)*4), zc);
    c0 = mfma16(a_hi, *(const half4*)(Pm + PACK_WO + (1*64+l)*4), c0);
    float4v c1 = mfma16(a_lo, *(const half4*)(Pm + PACK_WO + (2*64+l)*4), zc);
    c1 = mfma16(a_hi, *(const half4*)(Pm + PACK_WO + (3*64+l)*4), c1);
    float boc0 = bo[c], boc1 = bo[c+16];
    float t0[4], t1[4];
    #pragma unroll
    for (int reg = 0; reg < 4; ++reg) {
      size_t Rd = (size_t)(r0 + 4*g + reg);
      t0[reg] = c0[reg] + boc0 + xf[Rd*32 + c];
      t1[reg] = c1[reg] + boc1 + xf[Rd*32 + c + 16];
    }
    float g1c0 = g1v[c], g1c1 = g1v[c+16], b1c0 = b1v[c], b1c1 = b1v[c+16];
    float y0[4], y1[4];
    #pragma unroll
    for (int reg = 0; reg < 4; ++reg) {
      float s1 = t0[reg] + t1[reg];
      float s2 = t0[reg]*t0[reg] + t1[reg]*t1[reg];
      s1 += __shfl_xor(s1, 1); s1 += __shfl_xor(s1, 2);
      s1 += __shfl_xor(s1, 4); s1 += __shfl_xor(s1, 8);
      s2 += __shfl_xor(s2, 1); s2 += __shfl_xor(s2, 2);
      s2 += __shfl_xor(s2, 4); s2 += __shfl_xor(s2, 8);
      float m = s1*(1.f/32.f);
      float rv = rsqrtf(s2*(1.f/32.f) - m*m + 1e-5f);
      y0[reg] = (t0[reg]-m)*rv*g1c0 + b1c0;
      y1[reg] = (t1[reg]-m)*rv*g1c1 + b1c1;
    }
    #pragma unroll
    for (int reg = 0; reg < 4; ++reg) {
      yls[w][4*g+reg][c]      = (_Float16)y0[reg];
      yls[w][4*g+reg][c + 16] = (_Float16)y1[reg];
    }
    half4 ay_lo = *(const half4*)&yls[w][c][4*g];
    half4 ay_hi = *(const half4*)&yls[w][c][16 + 4*g];
    #pragma unroll
    for (int t = 0; t < 8; ++t) {
      float4v hc = mfma16(ay_lo, *(const half4*)(Pm + PACK_W1 + ((t*2+0)*64+l)*4), zc);
      hc = mfma16(ay_hi, *(const half4*)(Pm + PACK_W1 + ((t*2+1)*64+l)*4), hc);
      float bb = b1f[t*16 + c];
      #pragma unroll
      for (int reg = 0; reg < 4; ++reg)
        hls[w][4*g+reg][t*16 + c] = (_Float16)fmaxf(hc[reg] + bb, 0.f);
    }
    float4v z0 = zc, z1 = zc;
    #pragma unroll
    for (int kp = 0; kp < 8; ++kp) {
      half4 ah = *(const half4*)&hls[w][c][kp*16 + 4*g];
      z0 = mfma16(ah, *(const half4*)(Pm + PACK_W2 + ((0*8+kp)*64+l)*4), z0);
      z1 = mfma16(ah, *(const half4*)(Pm + PACK_W2 + ((1*8+kp)*64+l)*4), z1);
    }
    float b2c0 = b2f[c], b2c1 = b2f[c+16];
    float g2c0 = g2v[c], g2c1 = g2v[c+16], bt0 = b2v[c], bt1 = b2v[c+16];
    float xn0[4], xn1[4];
    #pragma unroll
    for (int reg = 0; reg < 4; ++reg) {
      float u0 = z0[reg] + b2c0 + y0[reg];
      float u1 = z1[reg] + b2c1 + y1[reg];
      float s1 = u0 + u1;
      float s2 = u0*u0 + u1*u1;
      s1 += __shfl_xor(s1, 1); s1 += __shfl_xor(s1, 2);
      s1 += __shfl_xor(s1, 4); s1 += __shfl_xor(s1, 8);
      s2 += __shfl_xor(s2, 1); s2 += __shfl_xor(s2, 2);
      s2 += __shfl_xor(s2, 4); s2 += __shfl_xor(s2, 8);
      float m = s1*(1.f/32.f);
      float rv = rsqrtf(s2*(1.f/32.f) - m*m + 1e-5f);
      xn0[reg] = (u0-m)*rv*g2c0 + bt0;
      xn1[reg] = (u1-m)*rv*g2c1 + bt1;
    }
    #pragma unroll
    for (int reg = 0; reg < 4; ++reg) {
      size_t Rd = (size_t)(r0 + 4*g + reg);
      xf[Rd*32 + c]      = xn0[reg];
      xf[Rd*32 + c + 16] = xn1[reg];
    }
    if (DO_QKV) {
      #pragma unroll
      for (int reg = 0; reg < 4; ++reg) {
        yls[w][4*g+reg][c]      = (_Float16)xn0[reg];
        yls[w][4*g+reg][c + 16] = (_Float16)xn1[reg];
      }
      ax_lo = *(const half4*)&yls[w][c][4*g];
      ax_hi = *(const half4*)&yls[w][c][16 + 4*g];
    }
  } else if (DO_QKV) {
    ax_lo = *(const half4*)(xh + (size_t)(r0 + c)*32 + 4*g);
    ax_hi = *(const half4*)(xh + (size_t)(r0 + c)*32 + 16 + 4*g);
  }

  if (DO_QKV) {
    #pragma unroll
    for (int t = 0; t < 6; ++t) {
      float4v qc = mfma16(ax_lo, *(const half4*)(Pq + PACK_WQ + ((t*2+0)*64+l)*4), zc);
      qc = mfma16(ax_hi, *(const half4*)(Pq + PACK_WQ + ((t*2+1)*64+l)*4), qc);
      const int colg = t*16 + c;
      float bb = bqkv[colg] * ((t < 2) ? QSCALE : 1.f);
      const int sec = t >> 1;
      const int hh = (colg & 31) >> 3, dd = colg & 7;
      #pragma unroll
      for (int reg = 0; reg < 4; ++reg) {
        unsigned Rd = (unsigned)(r0 + 4*g + reg);
        unsigned bI = Rd / 652u;
        unsigned p  = Rd - bI*652u;
        _Float16 v = (_Float16)(qc[reg] + bb);
        if (sec == 0)      qkh[((size_t)(bI*4+hh)*NPOS + p)*8 + dd] = v;
        else if (sec == 1) kbh[((size_t)(bI*4+hh)*NPOS + p)*8 + dd] = v;
        else               vth[((size_t)(bI*4+hh)*8 + dd)*NPOS + p] = v;
      }
    }
  }
}

// ------------------------------------------------------------------ attn ----
// Block per (b,h), 512 thr = 8 waves. Swizzled K LDS (conflict-free), V^T
// with ones-row at d=8 -> denominator comes free from the PV mfma.
#define KSTR 16    // f16 per K row (32B); halves XOR-swizzled by (row>>2)&3
#define VSTR 668   // f16 per V^T row; 334 words ≡ 2*odd -> rows on distinct banks
__global__ __launch_bounds__(512) void attn_kernel(
    const _Float16* __restrict__ qkh, const _Float16* __restrict__ kbh,
    const _Float16* __restrict__ vth, _Float16* __restrict__ oh)
{
  __shared__ _Float16 Klds[656*KSTR];    // 21.0 KB
  __shared__ _Float16 VTlds[16*VSTR];    // 21.4 KB (rows 0-7 V, 8 ones, 9-15 zero)
  int bh = blockIdx.x;
  int b = bh >> 2, h = bh & 3;
  int tid = threadIdx.x;
  const half4 z4 = {0,0,0,0};
  const half4 o4 = {(_Float16)1.f,(_Float16)1.f,(_Float16)1.f,(_Float16)1.f};
  // ---- stage K with XOR swizzle on the half4 slot
  for (int r = tid; r < 656; r += 512) {
    half4 a = z4, c = z4;
    if (r < NPOS) {
      a = *(const half4*)(kbh + ((size_t)bh*NPOS + r)*8);
      c = *(const half4*)(kbh + ((size_t)bh*NPOS + r)*8 + 4);
    }
    int sw = (r >> 2) & 3;
    _Float16* kr = Klds + r*KSTR;
    *(half4*)(kr + ((0^sw) << 2)) = a;
    *(half4*)(kr + ((1^sw) << 2)) = c;
    *(half4*)(kr + ((2^sw) << 2)) = z4;
    *(half4*)(kr + ((3^sw) << 2)) = z4;
  }
  // ---- stage V^T rows 0..15 (+ ones row d=8; cols >=652 zero everywhere)
  for (int i = tid; i < 16*167; i += 512) {
    int d = i / 167, kc = (i % 167)*4;
    half4 v = z4;
    if (kc < 652) {
      if (d < 8)       v = *(const half4*)(vth + ((size_t)bh*8 + d)*NPOS + kc);
      else if (d == 8) v = o4;
    }
    *(half4*)(VTlds + d*VSTR + kc) = v;
  }
  __syncthreads();

  int wave = tid >> 6, lane = tid & 63;
  int q16 = lane & 15;
  int kg  = lane >> 4;
  const int ksw = ((q16 >> 2) & 3) ^ kg;   // K read slot (row>>2 == q16>>2 mod 4)
  const float4v zc = {0.f,0.f,0.f,0.f};

  for (int qt = wave; qt < 41; qt += 8) {
    int qrow = qt*16 + q16;
    int qrc = qrow < NPOS ? qrow : NPOS-1;
    half4 qf = z4;
    if (kg < 2)
      qf = *(const half4*)(qkh + ((size_t)bh*NPOS + qrc)*8 + kg*4);
    float4v o = zc;
    for (int kt = 0; kt < 41; ++kt) {
      half4 kf = *(const half4*)(Klds + (kt*16 + q16)*KSTR + (ksw << 2));
      float4v s = __builtin_amdgcn_mfma_f32_16x16x16f16(kf, qf, zc, 0, 0, 0);
      half4 pf;
      pf[0] = (_Float16)__builtin_amdgcn_exp2f(s[0]);
      pf[1] = (_Float16)__builtin_amdgcn_exp2f(s[1]);
      pf[2] = (_Float16)__builtin_amdgcn_exp2f(s[2]);
      pf[3] = (_Float16)__builtin_amdgcn_exp2f(s[3]);
      half4 vf = *(const half4*)(VTlds + q16*VSTR + kt*16 + (kg << 2));
      o = __builtin_amdgcn_mfma_f32_16x16x16f16(pf, vf, o, 0, 0, 0);
    }
    // den for rows 4kg+reg sits in lane (kg*16 + 8)'s o[reg] (d=8 ones col).
    float dq[4];
    #pragma unroll
    for (int reg = 0; reg < 4; ++reg)
      dq[reg] = __shfl(o[reg], (lane & 48) | 8);
    if (q16 < 8) {
      #pragma unroll
      for (int reg = 0; reg < 4; ++reg) {
        int qo = qt*16 + 4*kg + reg;
        if (qo < NPOS) {
          oh[((size_t)(b*NPOS + qo))*32 + h*8 + q16] = (_Float16)(o[reg] / dq[reg]);
        }
      }
    }
  }
}

// --------------------------------------------------------------- readout ----
__global__ __launch_bounds__(256) void readout_kernel(
    const float* __restrict__ x,
    const float* __restrict__ Wtraj, const float* __restrict__ btraj,
    const float* __restrict__ Wint, const float* __restrict__ bint,
    float* __restrict__ dout)
{
  int idx = blockIdx.x*256 + threadIdx.x;
  if (idx >= NB*NVEH) return;
  int b = idx >> 6, n = idx & 63;
  int z = n >> 4, v = n & 15;
  int base = 4 + z*ZSTRIDE + 2 + v*10;
  float acc[16];
  #pragma unroll
  for (int i = 0; i < 16; ++i) acc[i] = btraj[i];
  #pragma unroll
  for (int t = 0; t < 4; ++t) {
    const float* xr = x + ((size_t)(b*NPOS + base + 6 + t))*32;
    #pragma unroll
    for (int k = 0; k < 32; ++k) {
      float xv = xr[k];
      const float* wr = Wtraj + (t*32 + k)*16;
      #pragma unroll
      for (int i = 0; i < 16; ++i) acc[i] += xv*wr[i];
    }
  }
  float* to = dout + (size_t)idx*16;
  #pragma unroll
  for (int i = 0; i < 16; ++i) to[i] = acc[i];
  float ai[8];
  #pragma unroll
  for (int j = 0; j < 8; ++j) ai[j] = bint[j];
  #pragma unroll
  for (int t = 0; t < 2; ++t) {
    const float* xr = x + ((size_t)(b*NPOS + base + 4 + t))*32;
    #pragma unroll
    for (int k = 0; k < 32; ++k) {
      float xv = xr[k];
      const float* wr = Wint + (t*32 + k)*8;
      #pragma unroll
      for (int j = 0; j < 8; ++j) ai[j] += xv*wr[j];
    }
  }
  float* io = dout + 131072 + (size_t)idx*8;
  #pragma unroll
  for (int j = 0; j < 8; ++j) io[j] = ai[j];
}

// ---------------------------------------------------------------- launch ----
extern "C" void kernel_launch(void* const* d_in, const int* in_sizes, int n_in,
                              void* d_out, int out_size, void* d_ws, size_t ws_size,
                              hipStream_t stream)
{
  const float* states  = (const float*)d_in[0];
  const float* road_ctx= (const float*)d_in[1];
  const float* pos_emb = (const float*)d_in[2];
  const float* Wp    = (const float*)d_in[4];  const float* bp    = (const float*)d_in[5];
  const float* Wv    = (const float*)d_in[6];  const float* bv    = (const float*)d_in[7];
  const float* Wh    = (const float*)d_in[8];  const float* bh    = (const float*)d_in[9];
  const float* Wc    = (const float*)d_in[10]; const float* bc    = (const float*)d_in[11];
  const float* Wflow = (const float*)d_in[12]; const float* bflow = (const float*)d_in[13];
  const float* Wsig  = (const float*)d_in[14]; const float* bsig  = (const float*)d_in[15];
  const float* Wtraj = (const float*)d_in[16]; const float* btraj = (const float*)d_in[17];
  const float* Wint  = (const float*)d_in[18]; const float* bint  = (const float*)d_in[19];
  const float* Wqkv  = (const float*)d_in[20]; const float* bqkv  = (const float*)d_in[21];
  const float* Wo    = (const float*)d_in[22]; const float* bo    = (const float*)d_in[23];
  const float* g1    = (const float*)d_in[24]; const float* b1ln  = (const float*)d_in[25];
  const float* W1    = (const float*)d_in[26]; const float* b1    = (const float*)d_in[27];
  const float* W2    = (const float*)d_in[28]; const float* b2    = (const float*)d_in[29];
  const float* g2    = (const float*)d_in[30]; const float* b2ln  = (const float*)d_in[31];

  // workspace layout
  float*     xf  = (float*)d_ws;                           // 10.7 MB fp32
  _Float16*  oh  = (_Float16*)(xf + (size_t)MROWS*32);     // 5.3 MB f16
  _Float16*  xh  = oh  + (size_t)MROWS*32;                 // 5.3 MB f16
  _Float16*  qkh = xh  + (size_t)MROWS*32;                 // 5.3 MB
  _Float16*  kbh = qkh + (size_t)512*NPOS*8;               // 5.3 MB
  _Float16*  vth = kbh + (size_t)512*NPOS*8;               // 5.3 MB
  _Float16*  P   = vth + (size_t)512*NPOS*8;               // 48 KB packed W

  canvas_kernel<<<NB*8, 256, 0, stream>>>(states, road_ctx, pos_emb,
      Wp, bp, Wv, bv, Wh, bh, Wc, bc, Wflow, bflow, Wsig, bsig, xf, xh);

  pack_kernel<<<2, 64, 0, stream>>>(Wqkv, Wo, W1, W2, P);

  const int eBlocks = MROWS/64;   // 1304

  // layer 0 qkv (from canvas xh; qkv weights layer 0)
  engine_kernel<false,true><<<eBlocks, 256, 0, stream>>>(
      nullptr, xh, xf, nullptr, P,
      nullptr, nullptr, nullptr, nullptr, nullptr, nullptr, nullptr,
      bqkv, qkh, kbh, vth);

  attn_kernel<<<NB*NH, 512, 0, stream>>>(qkh, kbh, vth, oh);

  // layer 0 proj+LN+FFN+LN (Pm = layer 0) fused with layer 1 qkv (Pq = layer 1)
  engine_kernel<true,true><<<eBlocks, 256, 0, stream>>>(
      oh, nullptr, xf, P, P + PACK_LAYER,
      bo, g1, b1ln, b1, b2, g2, b2ln,
      bqkv + 96, qkh, kbh, vth);

  attn_kernel<<<NB*NH, 512, 0, stream>>>(qkh, kbh, vth, oh);

  // layer 1 proj+LN+FFN+LN (Pm = layer 1)
  engine_kernel<true,false><<<eBlocks, 256, 0, stream>>>(
      oh, nullptr, xf, P + PACK_LAYER, nullptr,
      bo + 32, g1 + 32, b1ln + 32, b1 + 128, b2 + 32, g2 + 32, b2ln + 32,
      nullptr, nullptr, nullptr, nullptr);

  readout_kernel<<<(NB*NVEH + 255)/256, 256, 0, stream>>>(
      xf, Wtraj, btraj, Wint, bint, (float*)d_out);
}